// Round 14
// baseline (221.715 us; speedup 1.0000x reference)
//
#include <hip/hip_runtime.h>
#include <hip/hip_bf16.h>

#define NB    2
#define NK    2048
#define NPTS  16384
#define NBK   4096            // NB*NK
#define MSAMP 65536.0f        // NBK*16 samples per scale for BN0/BN1
#define MROW  4096.0f         // rows for final BN

// ---------------------------------------------------------------------------
// A: mega-kernel with UNIONED role LDS (21.5KB block -> 7 blocks/CU).
//  Blocks 0..511: ball-query grouping, 2 keypoints/wave (r11-verified loop).
//  Blocks 512..2711: BEV CHW->HWC transpose (r11-verified).
// ---------------------------------------------------------------------------
__global__ __launch_bounds__(256) void mega_kernel(
    const float* __restrict__ kp, const float* __restrict__ pts,
    const float* __restrict__ pfeat, const float* __restrict__ bev,
    float* __restrict__ g0buf, float* __restrict__ g1buf,
    int* __restrict__ cnt, float* __restrict__ part0,
    float* __restrict__ bevT)
{
  __shared__ __align__(16) char smem[21504];   // union of role layouts
  const int t = threadIdx.x;
  const int wave = t >> 6;
  const int lane = t & 63;

  if (blockIdx.x >= 512) {
    // ---- TRANSPOSE role: ttile[64][65] at smem+0 (16640 B)
    float (*ttile)[65] = (float (*)[65])smem;
    const int tb  = blockIdx.x - 512;     // 0..2199
    const int b   = tb / 1100;
    const int rem = tb % 1100;
    const int cg  = (rem / 275) * 64;     // channel group base
    const int sp0 = (rem % 275) * 64;     // spatial base (17600 = 275*64)
    #pragma unroll 4
    for (int i = 0; i < 16; i++) {
      const int c = cg + wave * 16 + i;
      ttile[wave * 16 + i][lane] = bev[((size_t)(b * 256 + c)) * 17600 + sp0 + lane];
    }
    __syncthreads();
    #pragma unroll 4
    for (int i = 0; i < 16; i++) {
      const int s = wave * 16 + i;
      bevT[((size_t)b * 17600 + sp0 + s) * 256 + cg + lane] = ttile[lane][s];
    }
    return;
  }

  // ---- GROUP role layout in smem:
  //   sxyz  [3072]f  @ 0      (12288 B)
  //   sfeat [1024]f  @ 12288  (4096 B)
  //   slots [4][2][2][16][4]f @ 16384 (4096 B)
  //   bred  [4][28]f @ 20480  (448 B)
  float* sxyz  = (float*)smem;
  float* sfeat = (float*)(smem + 12288);
  float (*slots)[2][2][16][4] = (float (*)[2][2][16][4])(smem + 16384);
  float (*bred)[28] = (float (*)[28])(smem + 20480);

  const int gb = blockIdx.x;            // 0..511
  const int bkA = gb * 8 + wave * 2;
  const int bkB = bkA + 1;
  const int b  = gb >> 8;               // 256 blocks per batch
  const float kxA = kp[bkA*3+0], kyA = kp[bkA*3+1], kzA = kp[bkA*3+2];
  const float kxB = kp[bkB*3+0], kyB = kp[bkB*3+1], kzB = kp[bkB*3+2];
  const float* px = pts   + (size_t)b * NPTS * 3;
  const float* pf = pfeat + (size_t)b * NPTS;
  int c0A = 0, c1A = 0, c0B = 0, c1B = 0;
  bool done = false;
  const unsigned long long below = (1ull << lane) - 1ull;

  for (int tile = 0; tile < 16; tile++) {
    __syncthreads();                    // protect LDS from previous tile's readers
    {
      const float4* gsrc = (const float4*)(px + tile * 3072);
      float4* ldst = (float4*)sxyz;
      ldst[t]       = gsrc[t];
      ldst[t + 256] = gsrc[t + 256];
      ldst[t + 512] = gsrc[t + 512];
      #pragma unroll
      for (int i = 0; i < 4; i++) sfeat[t + i * 256] = pf[tile * 1024 + t + i * 256];
    }
    __syncthreads();
    if (!done) {
      for (int inner = 0; inner < 16; inner++) {
        const int pp = inner * 64 + lane;
        const float x = sxyz[pp*3+0];
        const float y = sxyz[pp*3+1];
        const float z = sxyz[pp*3+2];
        const float dxA = x - kxA, dyA = y - kyA, dzA = z - kzA;
        const float d2A = dxA*dxA + dyA*dyA + dzA*dzA;
        const float dxB = x - kxB, dyB = y - kyB, dzB = z - kzB;
        const float d2B = dxB*dxB + dyB*dyB + dzB*dzB;
        const bool w1a = d2A < 0.64f;   // 0.8^2
        const bool w1b = d2B < 0.64f;
        const unsigned long long m1a = __ballot(w1a);
        const unsigned long long m1b = __ballot(w1b);
        if (m1a | m1b) {                // rare
          const bool w0a = d2A < 0.16f; // 0.4^2
          const bool w0b = d2B < 0.16f;
          const unsigned long long m0a = __ballot(w0a);
          const unsigned long long m0b = __ballot(w0b);
          const float f = sfeat[pp];
          {  // keypoint A
            const int o0 = c0A + __popcll(m0a & below);
            if (w0a && o0 < 16) {
              slots[wave][0][0][o0][0] = dxA; slots[wave][0][0][o0][1] = dyA;
              slots[wave][0][0][o0][2] = dzA; slots[wave][0][0][o0][3] = f;
            }
            const int o1 = c1A + __popcll(m1a & below);
            if (w1a && o1 < 16) {
              slots[wave][0][1][o1][0] = dxA; slots[wave][0][1][o1][1] = dyA;
              slots[wave][0][1][o1][2] = dzA; slots[wave][0][1][o1][3] = f;
            }
            c0A += __popcll(m0a);
            c1A += __popcll(m1a);
          }
          {  // keypoint B
            const int o0 = c0B + __popcll(m0b & below);
            if (w0b && o0 < 16) {
              slots[wave][1][0][o0][0] = dxB; slots[wave][1][0][o0][1] = dyB;
              slots[wave][1][0][o0][2] = dzB; slots[wave][1][0][o0][3] = f;
            }
            const int o1 = c1B + __popcll(m1b & below);
            if (w1b && o1 < 16) {
              slots[wave][1][1][o1][0] = dxB; slots[wave][1][1][o1][1] = dyB;
              slots[wave][1][1][o1][2] = dzB; slots[wave][1][1][o1][3] = f;
            }
            c0B += __popcll(m0b);
            c1B += __popcll(m1b);
          }
          if (c0A >= 16 && c0B >= 16) { done = true; break; }  // c1 >= c0 always
        }
      }
    }
  }
  __syncthreads();

  // padding: empty -> zeros, partial -> replicate slot 0.
  // kp = lane>>5, scale = (lane>>4)&1, slot = lane&15.
  {
    const int kpid = lane >> 5;
    const int s    = (lane >> 4) & 1;
    const int sl   = lane & 15;
    const int cs = kpid ? (s ? c1B : c0B) : (s ? c1A : c0A);
    if (cs == 0) {
      slots[wave][kpid][s][sl][0] = 0.f; slots[wave][kpid][s][sl][1] = 0.f;
      slots[wave][kpid][s][sl][2] = 0.f; slots[wave][kpid][s][sl][3] = 0.f;
    } else if (sl >= cs) {
      slots[wave][kpid][s][sl][0] = slots[wave][kpid][s][0][0];
      slots[wave][kpid][s][sl][1] = slots[wave][kpid][s][0][1];
      slots[wave][kpid][s][sl][2] = slots[wave][kpid][s][0][2];
      slots[wave][kpid][s][sl][3] = slots[wave][kpid][s][0][3];
    }
  }

  // write grouped data (coalesced, 64 floats per scale per keypoint)
  g0buf[(size_t)bkA * 64 + lane] = slots[wave][0][0][lane >> 2][lane & 3];
  g1buf[(size_t)bkA * 64 + lane] = slots[wave][0][1][lane >> 2][lane & 3];
  g0buf[(size_t)bkB * 64 + lane] = slots[wave][1][0][lane >> 2][lane & 3];
  g1buf[(size_t)bkB * 64 + lane] = slots[wave][1][1][lane >> 2][lane & 3];
  if (lane == 0) {
    cnt[bkA] = c0A; cnt[NBK + bkA] = c1A;
    cnt[bkB] = c0B; cnt[NBK + bkB] = c1B;
  }

  // BN0 moment partials: butterfly 16 then merge kpA+kpB across lane 32
  float v[14];
  {
    const int kpid = lane >> 5;
    const int s    = (lane >> 4) & 1;
    const int sl   = lane & 15;
    const float x0 = slots[wave][kpid][s][sl][0];
    const float x1 = slots[wave][kpid][s][sl][1];
    const float x2 = slots[wave][kpid][s][sl][2];
    const float x3 = slots[wave][kpid][s][sl][3];
    v[0] = x0; v[1] = x1; v[2] = x2; v[3] = x3;
    v[4] = x0*x0; v[5] = x0*x1; v[6]  = x0*x2; v[7]  = x0*x3;
    v[8] = x1*x1; v[9] = x1*x2; v[10] = x1*x3;
    v[11] = x2*x2; v[12] = x2*x3; v[13] = x3*x3;
  }
  #pragma unroll
  for (int d = 1; d < 16; d <<= 1) {
    #pragma unroll
    for (int i = 0; i < 14; i++) v[i] += __shfl_xor(v[i], d);
  }
  #pragma unroll
  for (int i = 0; i < 14; i++) v[i] += __shfl_xor(v[i], 32);  // merge kpA+kpB
  if (lane == 0 || lane == 16) {
    float* dst = &bred[wave][(lane >> 4) * 14];
    #pragma unroll
    for (int i = 0; i < 14; i++) dst[i] = v[i];
  }
  __syncthreads();
  if (t < 28) {
    part0[gb * 28 + t] = bred[0][t] + bred[1][t] + bred[2][t] + bred[3][t];
  }
}

// ---------------------------------------------------------------------------
// helper: compute BN0 params (sP[0:64]) from S0[28] sums — runs in-block
// ---------------------------------------------------------------------------
__device__ __forceinline__ void bn0_params(
    int t, const float* S0, const float* sW0a, const float* sW0b,
    const float* gm0s0, const float* bt0s0,
    const float* gm0s1, const float* bt0s1, float* sP)
{
  if (t < 32) {
    const int s = t >> 4, c = t & 15;
    const float* W  = s ? sW0b : sW0a;
    const float* G  = s ? gm0s1 : gm0s0;
    const float* Bt = s ? bt0s1 : bt0s0;
    const float* Sx = S0 + s * 14;
    const float w0 = W[c*4+0], w1 = W[c*4+1];
    const float w2 = W[c*4+2], w3 = W[c*4+3];
    const float inv = 1.0f / MSAMP;
    const float mean = (w0*Sx[0] + w1*Sx[1] + w2*Sx[2] + w3*Sx[3]) * inv;
    float e2 = w0*w0*Sx[4] + 2.f*w0*w1*Sx[5] + 2.f*w0*w2*Sx[6] + 2.f*w0*w3*Sx[7]
             + w1*w1*Sx[8] + 2.f*w1*w2*Sx[9] + 2.f*w1*w3*Sx[10]
             + w2*w2*Sx[11] + 2.f*w2*w3*Sx[12] + w3*w3*Sx[13];
    e2 *= inv;
    const float var = e2 - mean * mean;
    const float A = G[c] / sqrtf(var + 1e-5f);
    sP[s*32 + c]      = A;
    sP[s*32 + 16 + c] = Bt[c] - mean * A;
  }
}

// ---------------------------------------------------------------------------
// B: BN1 stats (local BN0 finalize over part0[512][28] + per-slot MLP
// layer01 + sum/sumsq). grid 256 x 256. part1[block][96].
// ---------------------------------------------------------------------------
__global__ __launch_bounds__(256) void stats1_kernel(
    const float* __restrict__ g0buf, const float* __restrict__ g1buf,
    const float* __restrict__ part0,
    const float* __restrict__ W0s0, const float* __restrict__ gm0s0, const float* __restrict__ bt0s0,
    const float* __restrict__ W0s1, const float* __restrict__ gm0s1, const float* __restrict__ bt0s1,
    const float* __restrict__ W1s0, const float* __restrict__ W1s1,
    float* __restrict__ part1)
{
  __shared__ float sW0a[64], sW0b[64], sW1a[256], sW1b[512], sP[64];
  __shared__ float tmp0[8][28], S0[28];
  __shared__ float red[16][96];
  const int t = threadIdx.x;
  if (t < 64) { sW0a[t] = W0s0[t]; sW0b[t] = W0s1[t]; }
  sW1a[t]       = W1s0[t];
  sW1b[t]       = W1s1[t];
  sW1b[t + 256] = W1s1[t + 256];
  for (int i = t; i < 16 * 96; i += 256) ((float*)red)[i] = 0.f;
  // local finalize0: sum part0[512][28]
  if (t < 224) {
    const int seg = t / 28, col = t % 28;
    float s = 0.f;
    for (int r = seg * 64; r < seg * 64 + 64; r++) s += part0[r * 28 + col];
    tmp0[seg][col] = s;
  }
  __syncthreads();
  if (t < 28) {
    float s = 0.f;
    #pragma unroll
    for (int g = 0; g < 8; g++) s += tmp0[g][t];
    S0[t] = s;
  }
  __syncthreads();
  bn0_params(t, S0, sW0a, sW0b, gm0s0, bt0s0, gm0s1, bt0s1, sP);
  __syncthreads();

  const int slot = blockIdx.x * 256 + t;
  const int wave = t >> 6, lane = t & 63;
  const int grp  = (wave << 2) | (lane >> 4);
  const bool leader = (lane & 15) == 0;

  float a1[16];
  {  // scale 0
    const float4 x = *(const float4*)(g0buf + (size_t)slot * 4);
    #pragma unroll
    for (int c = 0; c < 16; c++) {
      const float h = sW0a[c*4+0]*x.x + sW0a[c*4+1]*x.y + sW0a[c*4+2]*x.z + sW0a[c*4+3]*x.w;
      a1[c] = fmaxf(fmaf(sP[c], h, sP[16+c]), 0.f);
    }
    #pragma unroll
    for (int o = 0; o < 16; o++) {
      float h2 = 0.f;
      #pragma unroll
      for (int c = 0; c < 16; c++) h2 = fmaf(sW1a[o*16+c], a1[c], h2);
      float s = h2, q = h2 * h2;
      #pragma unroll
      for (int d = 1; d < 16; d <<= 1) { s += __shfl_xor(s, d); q += __shfl_xor(q, d); }
      if (leader) { red[grp][o] += s; red[grp][16+o] += q; }
    }
  }
  {  // scale 1
    const float4 x = *(const float4*)(g1buf + (size_t)slot * 4);
    #pragma unroll
    for (int c = 0; c < 16; c++) {
      const float h = sW0b[c*4+0]*x.x + sW0b[c*4+1]*x.y + sW0b[c*4+2]*x.z + sW0b[c*4+3]*x.w;
      a1[c] = fmaxf(fmaf(sP[32+c], h, sP[48+c]), 0.f);
    }
    #pragma unroll
    for (int o = 0; o < 32; o++) {
      float h2 = 0.f;
      #pragma unroll
      for (int c = 0; c < 16; c++) h2 = fmaf(sW1b[o*16+c], a1[c], h2);
      float s = h2, q = h2 * h2;
      #pragma unroll
      for (int d = 1; d < 16; d <<= 1) { s += __shfl_xor(s, d); q += __shfl_xor(q, d); }
      if (leader) { red[grp][32+o] += s; red[grp][64+o] += q; }
    }
  }
  __syncthreads();
  if (t < 96) {
    float s = 0.f;
    #pragma unroll
    for (int g = 0; g < 16; g++) s += red[g][t];
    part1[blockIdx.x * 96 + t] = s;
  }
}

// ---------------------------------------------------------------------------
// C: pool + fused GEMM, with inline coalesced BEV gather from bevT (HWC).
// grid 256 x 256, 16 keypoints(rows)/block.
// ---------------------------------------------------------------------------
__global__ __launch_bounds__(256) void poolgemm_kernel(
    const float* __restrict__ kp, const int* __restrict__ stridep,
    const float* __restrict__ bevT,
    const float* __restrict__ g0buf, const float* __restrict__ g1buf,
    const int* __restrict__ cnt,
    const float* __restrict__ part0, const float* __restrict__ part1,
    const float* __restrict__ W0s0, const float* __restrict__ gm0s0, const float* __restrict__ bt0s0,
    const float* __restrict__ W0s1, const float* __restrict__ gm0s1, const float* __restrict__ bt0s1,
    const float* __restrict__ W1s0, const float* __restrict__ gm1s0, const float* __restrict__ bt1s0,
    const float* __restrict__ W1s1, const float* __restrict__ gm1s1, const float* __restrict__ bt1s1,
    const float* __restrict__ Wf,
    float* __restrict__ fused, float* __restrict__ part2)
{
  __shared__ float sW0a[64], sW0b[64], sW1a[256], sW1b[512], sP[160];
  __shared__ float tmp0[8][28], S0[28];
  __shared__ float tmp1[2][96], S1[96];
  __shared__ __align__(16) float sF[16 * 304];
  const int t = threadIdx.x;
  const int bk0 = blockIdx.x * 16;

  // ---- BEV gather: row r, channel t. 4 coalesced 1KB reads per row. ----
  {
    const float st = (float)(*stridep);
    for (int r = 0; r < 16; r++) {
      const int bk = bk0 + r;
      const int b = bk >> 11;
      const float x = (kp[bk*3+0] - (-70.4f)) / 0.1f / st;
      const float y = (kp[bk*3+1] - (-40.0f)) / 0.1f / st;
      const int xf = (int)floorf(x), yf = (int)floorf(y);
      const int x0 = min(max(xf, 0), 175), x1 = min(max(xf + 1, 0), 175);
      const int y0 = min(max(yf, 0), 99),  y1 = min(max(yf + 1, 0), 99);
      const float x0f = (float)x0, x1f = (float)x1, y0f = (float)y0, y1f = (float)y1;
      const float wa = (x1f - x) * (y1f - y);
      const float wb = (x1f - x) * (y - y0f);
      const float wc = (x - x0f) * (y1f - y);
      const float wd = (x - x0f) * (y - y0f);
      const size_t pb = (size_t)b * 17600 * 256;
      const float Ia = bevT[pb + (size_t)(y0 * 176 + x0) * 256 + t];
      const float Ib = bevT[pb + (size_t)(y1 * 176 + x0) * 256 + t];
      const float Ic = bevT[pb + (size_t)(y0 * 176 + x1) * 256 + t];
      const float Id = bevT[pb + (size_t)(y1 * 176 + x1) * 256 + t];
      sF[r * 304 + t] = Ia * wa + Ib * wb + Ic * wc + Id * wd;
    }
  }

  if (t < 64)  { sW0a[t] = W0s0[t]; sW0b[t] = W0s1[t]; }
  sW1a[t]       = W1s0[t];
  sW1b[t]       = W1s1[t];
  sW1b[t + 256] = W1s1[t + 256];
  // local finalize0 over part0[512][28]
  if (t < 224) {
    const int seg = t / 28, col = t % 28;
    float s = 0.f;
    for (int r = seg * 64; r < seg * 64 + 64; r++) s += part0[r * 28 + col];
    tmp0[seg][col] = s;
  }
  __syncthreads();
  if (t < 28) {
    float s = 0.f;
    #pragma unroll
    for (int g = 0; g < 8; g++) s += tmp0[g][t];
    S0[t] = s;
  }
  if (t >= 32 && t < 224) {
    const int tt = t - 32;
    const int seg = tt / 96, col = tt % 96;
    float s = 0.f;
    for (int r = seg * 128; r < seg * 128 + 128; r++) s += part1[r * 96 + col];
    tmp1[seg][col] = s;
  }
  __syncthreads();
  bn0_params(t, S0, sW0a, sW0b, gm0s0, bt0s0, gm0s1, bt0s1, sP);
  if (t >= 64 && t < 160) {
    const int c = t - 64;
    S1[c] = tmp1[0][c] + tmp1[1][c];
  }
  __syncthreads();
  if (t < 48) {
    float sum, sq, G, Bv; int oA, oB;
    if (t < 16) { sum = S1[t];    sq = S1[16+t]; G = gm1s0[t]; Bv = bt1s0[t]; oA = 64+t;  oB = 80+t; }
    else { const int c = t - 16; sum = S1[32+c]; sq = S1[64+c]; G = gm1s1[c]; Bv = bt1s1[c]; oA = 96+c; oB = 128+c; }
    const float mean = sum / MSAMP;
    const float var  = sq / MSAMP - mean * mean;
    const float A = G / sqrtf(var + 1e-5f);
    sP[oA] = A;
    sP[oB] = Bv - mean * A;
  }
  __syncthreads();

  // ---- pool phase: 16 kp x 16 slots ----
  {
    const int lkp = t >> 4, slot = t & 15;
    const int bk = bk0 + lkp;
    const size_t si = (size_t)bk * 16 + slot;
    float a1[16], a2s0[16], a2s1[32];
    {
      const float4 x = *(const float4*)(g0buf + si * 4);
      #pragma unroll
      for (int c = 0; c < 16; c++) {
        const float h = sW0a[c*4+0]*x.x + sW0a[c*4+1]*x.y + sW0a[c*4+2]*x.z + sW0a[c*4+3]*x.w;
        a1[c] = fmaxf(fmaf(sP[c], h, sP[16+c]), 0.f);
      }
      #pragma unroll
      for (int o = 0; o < 16; o++) {
        float h2 = 0.f;
        #pragma unroll
        for (int c = 0; c < 16; c++) h2 = fmaf(sW1a[o*16+c], a1[c], h2);
        a2s0[o] = fmaxf(fmaf(sP[64+o], h2, sP[80+o]), 0.f);
      }
    }
    {
      const float4 x = *(const float4*)(g1buf + si * 4);
      #pragma unroll
      for (int c = 0; c < 16; c++) {
        const float h = sW0b[c*4+0]*x.x + sW0b[c*4+1]*x.y + sW0b[c*4+2]*x.z + sW0b[c*4+3]*x.w;
        a1[c] = fmaxf(fmaf(sP[32+c], h, sP[48+c]), 0.f);
      }
      #pragma unroll
      for (int o = 0; o < 32; o++) {
        float h2 = 0.f;
        #pragma unroll
        for (int c = 0; c < 16; c++) h2 = fmaf(sW1b[o*16+c], a1[c], h2);
        a2s1[o] = fmaxf(fmaf(sP[96+o], h2, sP[128+o]), 0.f);
      }
    }
    #pragma unroll
    for (int d = 1; d < 16; d <<= 1) {
      #pragma unroll
      for (int o = 0; o < 16; o++) a2s0[o] = fmaxf(a2s0[o], __shfl_xor(a2s0[o], d));
      #pragma unroll
      for (int o = 0; o < 32; o++) a2s1[o] = fmaxf(a2s1[o], __shfl_xor(a2s1[o], d));
    }
    if (slot == 0) {
      const int c0 = cnt[bk], c1 = cnt[NBK + bk];
      float* outp = sF + lkp * 304 + 256;
      #pragma unroll
      for (int o = 0; o < 16; o++) outp[o] = c0 ? a2s0[o] : 0.f;
      #pragma unroll
      for (int o = 0; o < 32; o++) outp[16 + o] = c1 ? a2s1[o] : 0.f;
    }
  }
  __syncthreads();

  // ---- GEMM phase: col c = t&127, rows rbase..rbase+8 ----
  {
    const int c = t & 127;
    const int rbase = (t >> 7) * 8;
    float acc[8];
    #pragma unroll
    for (int r = 0; r < 8; r++) acc[r] = 0.f;
    const float* wrow = Wf + (size_t)c * 304;
    for (int j4 = 0; j4 < 76; j4++) {
      const float4 w = *(const float4*)(wrow + j4 * 4);
      #pragma unroll
      for (int r = 0; r < 8; r++) {
        const float4 f = *(const float4*)(sF + (rbase + r) * 304 + j4 * 4);
        acc[r] = fmaf(w.x, f.x, acc[r]);
        acc[r] = fmaf(w.y, f.y, acc[r]);
        acc[r] = fmaf(w.z, f.z, acc[r]);
        acc[r] = fmaf(w.w, f.w, acc[r]);
      }
    }
    float s = 0.f, q = 0.f;
    #pragma unroll
    for (int r = 0; r < 8; r++) {
      fused[(size_t)(bk0 + rbase + r) * 128 + c] = acc[r];
      s += acc[r];
      q = fmaf(acc[r], acc[r], q);
    }
    const int prow = blockIdx.x * 2 + (t >> 7);
    part2[prow * 256 + c]       = s;
    part2[prow * 256 + 128 + c] = q;
  }
}

// ---------------------------------------------------------------------------
// D: out (local finalize2 + BN + relu). 128 blocks x 256 threads.
// ---------------------------------------------------------------------------
__global__ __launch_bounds__(256) void out_kernel(
    const float* __restrict__ fused, const float* __restrict__ part2,
    const float* __restrict__ gf, const float* __restrict__ bfp,
    float* __restrict__ out)
{
  __shared__ float sA[128], sB[128];
  __shared__ float tmp[2][128];
  const int t = threadIdx.x;
  {
    const int c = t & 127, which = t >> 7;
    float s = 0.f;
    for (int r = 0; r < 512; r++) s += part2[r * 256 + which * 128 + c];
    tmp[which][c] = s;
  }
  __syncthreads();
  if (t < 128) {
    const float mean = tmp[0][t] / MROW;
    const float var  = tmp[1][t] / MROW - mean * mean;
    const float A = gf[t] / sqrtf(var + 1e-5f);
    sA[t] = A;
    sB[t] = bfp[t] - mean * A;
  }
  __syncthreads();
  #pragma unroll
  for (int k = 0; k < 4; k++) {
    const int f4 = blockIdx.x * 1024 + k * 256 + t;   // 0..131071
    const int i = f4 * 4;
    const float4 v = *(const float4*)(fused + i);
    const int c = i & 127;
    float4 o;
    o.x = fmaxf(fmaf(v.x, sA[c+0], sB[c+0]), 0.f);
    o.y = fmaxf(fmaf(v.y, sA[c+1], sB[c+1]), 0.f);
    o.z = fmaxf(fmaf(v.z, sA[c+2], sB[c+2]), 0.f);
    o.w = fmaxf(fmaf(v.w, sA[c+3], sB[c+3]), 0.f);
    *(float4*)(out + i) = o;
  }
}

// ---------------------------------------------------------------------------
extern "C" void kernel_launch(void* const* d_in, const int* in_sizes, int n_in,
                              void* d_out, int out_size, void* d_ws, size_t ws_size,
                              hipStream_t stream)
{
  const float* kp    = (const float*)d_in[0];
  const float* pts   = (const float*)d_in[1];
  const float* pfeat = (const float*)d_in[2];
  const float* bev   = (const float*)d_in[3];
  const int*   strd  = (const int*)d_in[4];
  const float* W0s0  = (const float*)d_in[5];
  const float* g0s0  = (const float*)d_in[6];
  const float* b0s0  = (const float*)d_in[7];
  const float* W1s0  = (const float*)d_in[8];
  const float* g1s0  = (const float*)d_in[9];
  const float* b1s0  = (const float*)d_in[10];
  const float* W0s1  = (const float*)d_in[11];
  const float* g0s1  = (const float*)d_in[12];
  const float* b0s1  = (const float*)d_in[13];
  const float* W1s1  = (const float*)d_in[14];
  const float* g1s1  = (const float*)d_in[15];
  const float* b1s1  = (const float*)d_in[16];
  const float* Wf    = (const float*)d_in[17];
  const float* gf    = (const float*)d_in[18];
  const float* bfv   = (const float*)d_in[19];

  float* w      = (float*)d_ws;
  float* g0buf  = w;                        // 262144
  float* g1buf  = w + 262144;               // 262144
  float* fused  = w + 524288;               // 4096*128 = 524288
  float* part0  = w + 1048576;              // 512*28 (reserve 32768)
  float* part1  = w + 1081344;              // 256*96 = 24576
  float* part2  = w + 1105920;              // 512*256 = 131072
  int*   cnt    = (int*)(w + 1236992);      // 8192 ints
  float* bevT   = w + 1245184;              // 2*17600*256 = 9011200 (36 MB)

  hipLaunchKernelGGL(mega_kernel,  dim3(2712), dim3(256), 0, stream,
                     kp, pts, pfeat, bev, g0buf, g1buf, cnt, part0, bevT);
  hipLaunchKernelGGL(stats1_kernel, dim3(256), dim3(256), 0, stream,
                     g0buf, g1buf, part0,
                     W0s0, g0s0, b0s0, W0s1, g0s1, b0s1, W1s0, W1s1, part1);
  hipLaunchKernelGGL(poolgemm_kernel, dim3(256), dim3(256), 0, stream,
                     kp, strd, bevT, g0buf, g1buf, cnt, part0, part1,
                     W0s0, g0s0, b0s0, W0s1, g0s1, b0s1,
                     W1s0, g1s0, b1s0, W1s1, g1s1, b1s1,
                     Wf, fused, part2);
  hipLaunchKernelGGL(out_kernel,   dim3(128), dim3(256), 0, stream,
                     fused, part2, gf, bfv, (float*)d_out);
}

// Round 15
// 211.768 us; speedup vs baseline: 1.0470x; 1.0470x over previous
//
#include <hip/hip_runtime.h>
#include <hip/hip_bf16.h>

#define NB    2
#define NK    2048
#define NPTS  16384
#define NBK   4096            // NB*NK
#define MSAMP 65536.0f        // NBK*16 samples per scale for BN0/BN1
#define MROW  4096.0f         // rows for final BN

// ---------------------------------------------------------------------------
// A: mega-kernel with UNIONED role LDS (21.5KB block -> 7 blocks/CU).
//  Blocks 0..511: ball-query grouping, 2 keypoints/wave (r11-verified loop).
//  Blocks 512..2711: BEV CHW->HWC transpose (r11-verified).
// ---------------------------------------------------------------------------
__global__ __launch_bounds__(256) void mega_kernel(
    const float* __restrict__ kp, const float* __restrict__ pts,
    const float* __restrict__ pfeat, const float* __restrict__ bev,
    float* __restrict__ g0buf, float* __restrict__ g1buf,
    int* __restrict__ cnt, float* __restrict__ part0,
    float* __restrict__ bevT)
{
  __shared__ __align__(16) char smem[21504];   // union of role layouts
  const int t = threadIdx.x;
  const int wave = t >> 6;
  const int lane = t & 63;

  if (blockIdx.x >= 512) {
    // ---- TRANSPOSE role: ttile[64][65] at smem+0 (16640 B)
    float (*ttile)[65] = (float (*)[65])smem;
    const int tb  = blockIdx.x - 512;     // 0..2199
    const int b   = tb / 1100;
    const int rem = tb % 1100;
    const int cg  = (rem / 275) * 64;     // channel group base
    const int sp0 = (rem % 275) * 64;     // spatial base (17600 = 275*64)
    #pragma unroll 4
    for (int i = 0; i < 16; i++) {
      const int c = cg + wave * 16 + i;
      ttile[wave * 16 + i][lane] = bev[((size_t)(b * 256 + c)) * 17600 + sp0 + lane];
    }
    __syncthreads();
    #pragma unroll 4
    for (int i = 0; i < 16; i++) {
      const int s = wave * 16 + i;
      bevT[((size_t)b * 17600 + sp0 + s) * 256 + cg + lane] = ttile[lane][s];
    }
    return;
  }

  // ---- GROUP role layout in smem:
  float* sxyz  = (float*)smem;                              // 3072 f
  float* sfeat = (float*)(smem + 12288);                    // 1024 f
  float (*slots)[2][2][16][4] = (float (*)[2][2][16][4])(smem + 16384);
  float (*bred)[28] = (float (*)[28])(smem + 20480);

  const int gb = blockIdx.x;            // 0..511
  const int bkA = gb * 8 + wave * 2;
  const int bkB = bkA + 1;
  const int b  = gb >> 8;               // 256 blocks per batch
  const float kxA = kp[bkA*3+0], kyA = kp[bkA*3+1], kzA = kp[bkA*3+2];
  const float kxB = kp[bkB*3+0], kyB = kp[bkB*3+1], kzB = kp[bkB*3+2];
  const float* px = pts   + (size_t)b * NPTS * 3;
  const float* pf = pfeat + (size_t)b * NPTS;
  int c0A = 0, c1A = 0, c0B = 0, c1B = 0;
  bool done = false;
  const unsigned long long below = (1ull << lane) - 1ull;

  for (int tile = 0; tile < 16; tile++) {
    __syncthreads();                    // protect LDS from previous tile's readers
    {
      const float4* gsrc = (const float4*)(px + tile * 3072);
      float4* ldst = (float4*)sxyz;
      ldst[t]       = gsrc[t];
      ldst[t + 256] = gsrc[t + 256];
      ldst[t + 512] = gsrc[t + 512];
      #pragma unroll
      for (int i = 0; i < 4; i++) sfeat[t + i * 256] = pf[tile * 1024 + t + i * 256];
    }
    __syncthreads();
    if (!done) {
      for (int inner = 0; inner < 16; inner++) {
        const int pp = inner * 64 + lane;
        const float x = sxyz[pp*3+0];
        const float y = sxyz[pp*3+1];
        const float z = sxyz[pp*3+2];
        const float dxA = x - kxA, dyA = y - kyA, dzA = z - kzA;
        const float d2A = dxA*dxA + dyA*dyA + dzA*dzA;
        const float dxB = x - kxB, dyB = y - kyB, dzB = z - kzB;
        const float d2B = dxB*dxB + dyB*dyB + dzB*dzB;
        const bool w1a = d2A < 0.64f;   // 0.8^2
        const bool w1b = d2B < 0.64f;
        const unsigned long long m1a = __ballot(w1a);
        const unsigned long long m1b = __ballot(w1b);
        if (m1a | m1b) {                // rare
          const bool w0a = d2A < 0.16f; // 0.4^2
          const bool w0b = d2B < 0.16f;
          const unsigned long long m0a = __ballot(w0a);
          const unsigned long long m0b = __ballot(w0b);
          const float f = sfeat[pp];
          {  // keypoint A
            const int o0 = c0A + __popcll(m0a & below);
            if (w0a && o0 < 16) {
              slots[wave][0][0][o0][0] = dxA; slots[wave][0][0][o0][1] = dyA;
              slots[wave][0][0][o0][2] = dzA; slots[wave][0][0][o0][3] = f;
            }
            const int o1 = c1A + __popcll(m1a & below);
            if (w1a && o1 < 16) {
              slots[wave][0][1][o1][0] = dxA; slots[wave][0][1][o1][1] = dyA;
              slots[wave][0][1][o1][2] = dzA; slots[wave][0][1][o1][3] = f;
            }
            c0A += __popcll(m0a);
            c1A += __popcll(m1a);
          }
          {  // keypoint B
            const int o0 = c0B + __popcll(m0b & below);
            if (w0b && o0 < 16) {
              slots[wave][1][0][o0][0] = dxB; slots[wave][1][0][o0][1] = dyB;
              slots[wave][1][0][o0][2] = dzB; slots[wave][1][0][o0][3] = f;
            }
            const int o1 = c1B + __popcll(m1b & below);
            if (w1b && o1 < 16) {
              slots[wave][1][1][o1][0] = dxB; slots[wave][1][1][o1][1] = dyB;
              slots[wave][1][1][o1][2] = dzB; slots[wave][1][1][o1][3] = f;
            }
            c0B += __popcll(m0b);
            c1B += __popcll(m1b);
          }
          if (c0A >= 16 && c0B >= 16) { done = true; break; }  // c1 >= c0 always
        }
      }
    }
  }
  __syncthreads();

  // padding: empty -> zeros, partial -> replicate slot 0.
  {
    const int kpid = lane >> 5;
    const int s    = (lane >> 4) & 1;
    const int sl   = lane & 15;
    const int cs = kpid ? (s ? c1B : c0B) : (s ? c1A : c0A);
    if (cs == 0) {
      slots[wave][kpid][s][sl][0] = 0.f; slots[wave][kpid][s][sl][1] = 0.f;
      slots[wave][kpid][s][sl][2] = 0.f; slots[wave][kpid][s][sl][3] = 0.f;
    } else if (sl >= cs) {
      slots[wave][kpid][s][sl][0] = slots[wave][kpid][s][0][0];
      slots[wave][kpid][s][sl][1] = slots[wave][kpid][s][0][1];
      slots[wave][kpid][s][sl][2] = slots[wave][kpid][s][0][2];
      slots[wave][kpid][s][sl][3] = slots[wave][kpid][s][0][3];
    }
  }

  // write grouped data (coalesced, 64 floats per scale per keypoint)
  g0buf[(size_t)bkA * 64 + lane] = slots[wave][0][0][lane >> 2][lane & 3];
  g1buf[(size_t)bkA * 64 + lane] = slots[wave][0][1][lane >> 2][lane & 3];
  g0buf[(size_t)bkB * 64 + lane] = slots[wave][1][0][lane >> 2][lane & 3];
  g1buf[(size_t)bkB * 64 + lane] = slots[wave][1][1][lane >> 2][lane & 3];
  if (lane == 0) {
    cnt[bkA] = c0A; cnt[NBK + bkA] = c1A;
    cnt[bkB] = c0B; cnt[NBK + bkB] = c1B;
  }

  // BN0 moment partials: butterfly 16 then merge kpA+kpB across lane 32
  float v[14];
  {
    const int kpid = lane >> 5;
    const int s    = (lane >> 4) & 1;
    const int sl   = lane & 15;
    const float x0 = slots[wave][kpid][s][sl][0];
    const float x1 = slots[wave][kpid][s][sl][1];
    const float x2 = slots[wave][kpid][s][sl][2];
    const float x3 = slots[wave][kpid][s][sl][3];
    v[0] = x0; v[1] = x1; v[2] = x2; v[3] = x3;
    v[4] = x0*x0; v[5] = x0*x1; v[6]  = x0*x2; v[7]  = x0*x3;
    v[8] = x1*x1; v[9] = x1*x2; v[10] = x1*x3;
    v[11] = x2*x2; v[12] = x2*x3; v[13] = x3*x3;
  }
  #pragma unroll
  for (int d = 1; d < 16; d <<= 1) {
    #pragma unroll
    for (int i = 0; i < 14; i++) v[i] += __shfl_xor(v[i], d);
  }
  #pragma unroll
  for (int i = 0; i < 14; i++) v[i] += __shfl_xor(v[i], 32);  // merge kpA+kpB
  if (lane == 0 || lane == 16) {
    float* dst = &bred[wave][(lane >> 4) * 14];
    #pragma unroll
    for (int i = 0; i < 14; i++) dst[i] = v[i];
  }
  __syncthreads();
  if (t < 28) {
    part0[gb * 28 + t] = bred[0][t] + bred[1][t] + bred[2][t] + bred[3][t];
  }
}

// ---------------------------------------------------------------------------
// helper: compute BN0 params (sP[0:64]) from S0[28] sums — runs in-block
// ---------------------------------------------------------------------------
__device__ __forceinline__ void bn0_params(
    int t, const float* S0, const float* sW0a, const float* sW0b,
    const float* gm0s0, const float* bt0s0,
    const float* gm0s1, const float* bt0s1, float* sP)
{
  if (t < 32) {
    const int s = t >> 4, c = t & 15;
    const float* W  = s ? sW0b : sW0a;
    const float* G  = s ? gm0s1 : gm0s0;
    const float* Bt = s ? bt0s1 : bt0s0;
    const float* Sx = S0 + s * 14;
    const float w0 = W[c*4+0], w1 = W[c*4+1];
    const float w2 = W[c*4+2], w3 = W[c*4+3];
    const float inv = 1.0f / MSAMP;
    const float mean = (w0*Sx[0] + w1*Sx[1] + w2*Sx[2] + w3*Sx[3]) * inv;
    float e2 = w0*w0*Sx[4] + 2.f*w0*w1*Sx[5] + 2.f*w0*w2*Sx[6] + 2.f*w0*w3*Sx[7]
             + w1*w1*Sx[8] + 2.f*w1*w2*Sx[9] + 2.f*w1*w3*Sx[10]
             + w2*w2*Sx[11] + 2.f*w2*w3*Sx[12] + w3*w3*Sx[13];
    e2 *= inv;
    const float var = e2 - mean * mean;
    const float A = G[c] / sqrtf(var + 1e-5f);
    sP[s*32 + c]      = A;
    sP[s*32 + 16 + c] = Bt[c] - mean * A;
  }
}

// ---------------------------------------------------------------------------
// B: BN1 stats. grid 256 x 256. part1[block][96]. part0 has 512 rows.
// ---------------------------------------------------------------------------
__global__ __launch_bounds__(256) void stats1_kernel(
    const float* __restrict__ g0buf, const float* __restrict__ g1buf,
    const float* __restrict__ part0,
    const float* __restrict__ W0s0, const float* __restrict__ gm0s0, const float* __restrict__ bt0s0,
    const float* __restrict__ W0s1, const float* __restrict__ gm0s1, const float* __restrict__ bt0s1,
    const float* __restrict__ W1s0, const float* __restrict__ W1s1,
    float* __restrict__ part1)
{
  __shared__ float sW0a[64], sW0b[64], sW1a[256], sW1b[512], sP[64];
  __shared__ float tmp0[8][28], S0[28];
  __shared__ float red[16][96];
  const int t = threadIdx.x;
  if (t < 64) { sW0a[t] = W0s0[t]; sW0b[t] = W0s1[t]; }
  sW1a[t]       = W1s0[t];
  sW1b[t]       = W1s1[t];
  sW1b[t + 256] = W1s1[t + 256];
  for (int i = t; i < 16 * 96; i += 256) ((float*)red)[i] = 0.f;
  // local finalize0: sum part0[512][28]
  if (t < 224) {
    const int seg = t / 28, col = t % 28;
    float s = 0.f;
    for (int r = seg * 64; r < seg * 64 + 64; r++) s += part0[r * 28 + col];
    tmp0[seg][col] = s;
  }
  __syncthreads();
  if (t < 28) {
    float s = 0.f;
    #pragma unroll
    for (int g = 0; g < 8; g++) s += tmp0[g][t];
    S0[t] = s;
  }
  __syncthreads();
  bn0_params(t, S0, sW0a, sW0b, gm0s0, bt0s0, gm0s1, bt0s1, sP);
  __syncthreads();

  const int slot = blockIdx.x * 256 + t;
  const int wave = t >> 6, lane = t & 63;
  const int grp  = (wave << 2) | (lane >> 4);
  const bool leader = (lane & 15) == 0;

  float a1[16];
  {  // scale 0
    const float4 x = *(const float4*)(g0buf + (size_t)slot * 4);
    #pragma unroll
    for (int c = 0; c < 16; c++) {
      const float h = sW0a[c*4+0]*x.x + sW0a[c*4+1]*x.y + sW0a[c*4+2]*x.z + sW0a[c*4+3]*x.w;
      a1[c] = fmaxf(fmaf(sP[c], h, sP[16+c]), 0.f);
    }
    #pragma unroll
    for (int o = 0; o < 16; o++) {
      float h2 = 0.f;
      #pragma unroll
      for (int c = 0; c < 16; c++) h2 = fmaf(sW1a[o*16+c], a1[c], h2);
      float s = h2, q = h2 * h2;
      #pragma unroll
      for (int d = 1; d < 16; d <<= 1) { s += __shfl_xor(s, d); q += __shfl_xor(q, d); }
      if (leader) { red[grp][o] += s; red[grp][16+o] += q; }
    }
  }
  {  // scale 1
    const float4 x = *(const float4*)(g1buf + (size_t)slot * 4);
    #pragma unroll
    for (int c = 0; c < 16; c++) {
      const float h = sW0b[c*4+0]*x.x + sW0b[c*4+1]*x.y + sW0b[c*4+2]*x.z + sW0b[c*4+3]*x.w;
      a1[c] = fmaxf(fmaf(sP[32+c], h, sP[48+c]), 0.f);
    }
    #pragma unroll
    for (int o = 0; o < 32; o++) {
      float h2 = 0.f;
      #pragma unroll
      for (int c = 0; c < 16; c++) h2 = fmaf(sW1b[o*16+c], a1[c], h2);
      float s = h2, q = h2 * h2;
      #pragma unroll
      for (int d = 1; d < 16; d <<= 1) { s += __shfl_xor(s, d); q += __shfl_xor(q, d); }
      if (leader) { red[grp][32+o] += s; red[grp][64+o] += q; }
    }
  }
  __syncthreads();
  if (t < 96) {
    float s = 0.f;
    #pragma unroll
    for (int g = 0; g < 16; g++) s += red[g][t];
    part1[blockIdx.x * 96 + t] = s;
  }
}

// ---------------------------------------------------------------------------
// C: pool + fused GEMM + inline coalesced BEV gather from bevT (HWC).
// grid 512 x 256, 8 keypoints(rows)/block (2 blocks/CU). kp staged in LDS,
// gather fully unrolled -> pipelined loads.
// ---------------------------------------------------------------------------
__global__ __launch_bounds__(256) void poolgemm_kernel(
    const float* __restrict__ kp, const int* __restrict__ stridep,
    const float* __restrict__ bevT,
    const float* __restrict__ g0buf, const float* __restrict__ g1buf,
    const int* __restrict__ cnt,
    const float* __restrict__ part0, const float* __restrict__ part1,
    const float* __restrict__ W0s0, const float* __restrict__ gm0s0, const float* __restrict__ bt0s0,
    const float* __restrict__ W0s1, const float* __restrict__ gm0s1, const float* __restrict__ bt0s1,
    const float* __restrict__ W1s0, const float* __restrict__ gm1s0, const float* __restrict__ bt1s0,
    const float* __restrict__ W1s1, const float* __restrict__ gm1s1, const float* __restrict__ bt1s1,
    const float* __restrict__ Wf,
    float* __restrict__ fused, float* __restrict__ part2)
{
  __shared__ float sW0a[64], sW0b[64], sW1a[256], sW1b[512], sP[160];
  __shared__ float tmp0[8][28], S0[28];
  __shared__ float tmp1[2][96], S1[96];
  __shared__ float skp[24];
  __shared__ float t2s[2][128], t2q[2][128];
  __shared__ __align__(16) float sF[8 * 304];
  const int t = threadIdx.x;
  const int bk0 = blockIdx.x * 8;

  if (t < 24) skp[t] = kp[(size_t)bk0 * 3 + t];
  if (t < 64)  { sW0a[t] = W0s0[t]; sW0b[t] = W0s1[t]; }
  sW1a[t]       = W1s0[t];
  sW1b[t]       = W1s1[t];
  sW1b[t + 256] = W1s1[t + 256];
  // local finalize0 over part0[512][28]
  if (t < 224) {
    const int seg = t / 28, col = t % 28;
    float s = 0.f;
    for (int r = seg * 64; r < seg * 64 + 64; r++) s += part0[r * 28 + col];
    tmp0[seg][col] = s;
  }
  __syncthreads();

  // ---- BEV gather: channel t, 8 rows unrolled (32 independent loads) ----
  {
    const float st = (float)(*stridep);
    const int b = bk0 >> 11;             // all 8 rows in same batch (8 | 2048)
    const size_t pb = (size_t)b * 17600 * 256;
    #pragma unroll
    for (int r = 0; r < 8; r++) {
      const float x = (skp[r*3+0] - (-70.4f)) / 0.1f / st;
      const float y = (skp[r*3+1] - (-40.0f)) / 0.1f / st;
      const int xf = (int)floorf(x), yf = (int)floorf(y);
      const int x0 = min(max(xf, 0), 175), x1 = min(max(xf + 1, 0), 175);
      const int y0 = min(max(yf, 0), 99),  y1 = min(max(yf + 1, 0), 99);
      const float x0f = (float)x0, x1f = (float)x1, y0f = (float)y0, y1f = (float)y1;
      const float wa = (x1f - x) * (y1f - y);
      const float wb = (x1f - x) * (y - y0f);
      const float wc = (x - x0f) * (y1f - y);
      const float wd = (x - x0f) * (y - y0f);
      const float Ia = bevT[pb + (size_t)(y0 * 176 + x0) * 256 + t];
      const float Ib = bevT[pb + (size_t)(y1 * 176 + x0) * 256 + t];
      const float Ic = bevT[pb + (size_t)(y0 * 176 + x1) * 256 + t];
      const float Id = bevT[pb + (size_t)(y1 * 176 + x1) * 256 + t];
      sF[r * 304 + t] = Ia * wa + Ib * wb + Ic * wc + Id * wd;
    }
  }

  if (t < 28) {
    float s = 0.f;
    #pragma unroll
    for (int g = 0; g < 8; g++) s += tmp0[g][t];
    S0[t] = s;
  }
  if (t >= 32 && t < 224) {
    const int tt = t - 32;
    const int seg = tt / 96, col = tt % 96;
    float s = 0.f;
    for (int r = seg * 128; r < seg * 128 + 128; r++) s += part1[r * 96 + col];
    tmp1[seg][col] = s;
  }
  __syncthreads();
  bn0_params(t, S0, sW0a, sW0b, gm0s0, bt0s0, gm0s1, bt0s1, sP);
  if (t >= 64 && t < 160) {
    const int c = t - 64;
    S1[c] = tmp1[0][c] + tmp1[1][c];
  }
  __syncthreads();
  if (t < 48) {
    float sum, sq, G, Bv; int oA, oB;
    if (t < 16) { sum = S1[t];    sq = S1[16+t]; G = gm1s0[t]; Bv = bt1s0[t]; oA = 64+t;  oB = 80+t; }
    else { const int c = t - 16; sum = S1[32+c]; sq = S1[64+c]; G = gm1s1[c]; Bv = bt1s1[c]; oA = 96+c; oB = 128+c; }
    const float mean = sum / MSAMP;
    const float var  = sq / MSAMP - mean * mean;
    const float A = G / sqrtf(var + 1e-5f);
    sP[oA] = A;
    sP[oB] = Bv - mean * A;
  }
  __syncthreads();

  // ---- pool phase: 8 kp x 16 slots (threads 0..127) ----
  if (t < 128) {
    const int lkp = t >> 4, slot = t & 15;
    const int bk = bk0 + lkp;
    const size_t si = (size_t)bk * 16 + slot;
    float a1[16], a2s0[16], a2s1[32];
    {
      const float4 x = *(const float4*)(g0buf + si * 4);
      #pragma unroll
      for (int c = 0; c < 16; c++) {
        const float h = sW0a[c*4+0]*x.x + sW0a[c*4+1]*x.y + sW0a[c*4+2]*x.z + sW0a[c*4+3]*x.w;
        a1[c] = fmaxf(fmaf(sP[c], h, sP[16+c]), 0.f);
      }
      #pragma unroll
      for (int o = 0; o < 16; o++) {
        float h2 = 0.f;
        #pragma unroll
        for (int c = 0; c < 16; c++) h2 = fmaf(sW1a[o*16+c], a1[c], h2);
        a2s0[o] = fmaxf(fmaf(sP[64+o], h2, sP[80+o]), 0.f);
      }
    }
    {
      const float4 x = *(const float4*)(g1buf + si * 4);
      #pragma unroll
      for (int c = 0; c < 16; c++) {
        const float h = sW0b[c*4+0]*x.x + sW0b[c*4+1]*x.y + sW0b[c*4+2]*x.z + sW0b[c*4+3]*x.w;
        a1[c] = fmaxf(fmaf(sP[32+c], h, sP[48+c]), 0.f);
      }
      #pragma unroll
      for (int o = 0; o < 32; o++) {
        float h2 = 0.f;
        #pragma unroll
        for (int c = 0; c < 16; c++) h2 = fmaf(sW1b[o*16+c], a1[c], h2);
        a2s1[o] = fmaxf(fmaf(sP[96+o], h2, sP[128+o]), 0.f);
      }
    }
    #pragma unroll
    for (int d = 1; d < 16; d <<= 1) {
      #pragma unroll
      for (int o = 0; o < 16; o++) a2s0[o] = fmaxf(a2s0[o], __shfl_xor(a2s0[o], d));
      #pragma unroll
      for (int o = 0; o < 32; o++) a2s1[o] = fmaxf(a2s1[o], __shfl_xor(a2s1[o], d));
    }
    if (slot == 0) {
      const int c0 = cnt[bk], c1 = cnt[NBK + bk];
      float* outp = sF + lkp * 304 + 256;
      #pragma unroll
      for (int o = 0; o < 16; o++) outp[o] = c0 ? a2s0[o] : 0.f;
      #pragma unroll
      for (int o = 0; o < 32; o++) outp[16 + o] = c1 ? a2s1[o] : 0.f;
    }
  }
  __syncthreads();

  // ---- GEMM phase: col c = t&127, rows rbase..rbase+4 ----
  {
    const int c = t & 127;
    const int half = t >> 7;
    const int rbase = half * 4;
    float acc[4];
    #pragma unroll
    for (int r = 0; r < 4; r++) acc[r] = 0.f;
    const float* wrow = Wf + (size_t)c * 304;
    for (int j4 = 0; j4 < 76; j4++) {
      const float4 w = *(const float4*)(wrow + j4 * 4);
      #pragma unroll
      for (int r = 0; r < 4; r++) {
        const float4 f = *(const float4*)(sF + (rbase + r) * 304 + j4 * 4);
        acc[r] = fmaf(w.x, f.x, acc[r]);
        acc[r] = fmaf(w.y, f.y, acc[r]);
        acc[r] = fmaf(w.z, f.z, acc[r]);
        acc[r] = fmaf(w.w, f.w, acc[r]);
      }
    }
    float s = 0.f, q = 0.f;
    #pragma unroll
    for (int r = 0; r < 4; r++) {
      fused[(size_t)(bk0 + rbase + r) * 128 + c] = acc[r];
      s += acc[r];
      q = fmaf(acc[r], acc[r], q);
    }
    t2s[half][c] = s;
    t2q[half][c] = q;
  }
  __syncthreads();
  if (t < 128) {
    part2[blockIdx.x * 256 + t]       = t2s[0][t] + t2s[1][t];
    part2[blockIdx.x * 256 + 128 + t] = t2q[0][t] + t2q[1][t];
  }
}

// ---------------------------------------------------------------------------
// D: out (local finalize2 + BN + relu). 128 blocks x 256 threads.
// ---------------------------------------------------------------------------
__global__ __launch_bounds__(256) void out_kernel(
    const float* __restrict__ fused, const float* __restrict__ part2,
    const float* __restrict__ gf, const float* __restrict__ bfp,
    float* __restrict__ out)
{
  __shared__ float sA[128], sB[128];
  __shared__ float tmp[2][128];
  const int t = threadIdx.x;
  {
    const int c = t & 127, which = t >> 7;
    float s = 0.f;
    for (int r = 0; r < 512; r++) s += part2[r * 256 + which * 128 + c];
    tmp[which][c] = s;
  }
  __syncthreads();
  if (t < 128) {
    const float mean = tmp[0][t] / MROW;
    const float var  = tmp[1][t] / MROW - mean * mean;
    const float A = gf[t] / sqrtf(var + 1e-5f);
    sA[t] = A;
    sB[t] = bfp[t] - mean * A;
  }
  __syncthreads();
  #pragma unroll
  for (int k = 0; k < 4; k++) {
    const int f4 = blockIdx.x * 1024 + k * 256 + t;   // 0..131071
    const int i = f4 * 4;
    const float4 v = *(const float4*)(fused + i);
    const int c = i & 127;
    float4 o;
    o.x = fmaxf(fmaf(v.x, sA[c+0], sB[c+0]), 0.f);
    o.y = fmaxf(fmaf(v.y, sA[c+1], sB[c+1]), 0.f);
    o.z = fmaxf(fmaf(v.z, sA[c+2], sB[c+2]), 0.f);
    o.w = fmaxf(fmaf(v.w, sA[c+3], sB[c+3]), 0.f);
    *(float4*)(out + i) = o;
  }
}

// ---------------------------------------------------------------------------
extern "C" void kernel_launch(void* const* d_in, const int* in_sizes, int n_in,
                              void* d_out, int out_size, void* d_ws, size_t ws_size,
                              hipStream_t stream)
{
  const float* kp    = (const float*)d_in[0];
  const float* pts   = (const float*)d_in[1];
  const float* pfeat = (const float*)d_in[2];
  const float* bev   = (const float*)d_in[3];
  const int*   strd  = (const int*)d_in[4];
  const float* W0s0  = (const float*)d_in[5];
  const float* g0s0  = (const float*)d_in[6];
  const float* b0s0  = (const float*)d_in[7];
  const float* W1s0  = (const float*)d_in[8];
  const float* g1s0  = (const float*)d_in[9];
  const float* b1s0  = (const float*)d_in[10];
  const float* W0s1  = (const float*)d_in[11];
  const float* g0s1  = (const float*)d_in[12];
  const float* b0s1  = (const float*)d_in[13];
  const float* W1s1  = (const float*)d_in[14];
  const float* g1s1  = (const float*)d_in[15];
  const float* b1s1  = (const float*)d_in[16];
  const float* Wf    = (const float*)d_in[17];
  const float* gf    = (const float*)d_in[18];
  const float* bfv   = (const float*)d_in[19];

  float* w      = (float*)d_ws;
  float* g0buf  = w;                        // 262144
  float* g1buf  = w + 262144;               // 262144
  float* fused  = w + 524288;               // 4096*128 = 524288
  float* part0  = w + 1048576;              // 512*28 (reserve 32768)
  float* part1  = w + 1081344;              // 256*96 = 24576
  float* part2  = w + 1105920;              // 512*256 = 131072
  int*   cnt    = (int*)(w + 1236992);      // 8192 ints
  float* bevT   = w + 1245184;              // 2*17600*256 = 9011200 (36 MB)

  hipLaunchKernelGGL(mega_kernel,  dim3(2712), dim3(256), 0, stream,
                     kp, pts, pfeat, bev, g0buf, g1buf, cnt, part0, bevT);
  hipLaunchKernelGGL(stats1_kernel, dim3(256), dim3(256), 0, stream,
                     g0buf, g1buf, part0,
                     W0s0, g0s0, b0s0, W0s1, g0s1, b0s1, W1s0, W1s1, part1);
  hipLaunchKernelGGL(poolgemm_kernel, dim3(512), dim3(256), 0, stream,
                     kp, strd, bevT, g0buf, g1buf, cnt, part0, part1,
                     W0s0, g0s0, b0s0, W0s1, g0s1, b0s1,
                     W1s0, g1s0, b1s0, W1s1, g1s1, b1s1,
                     Wf, fused, part2);
  hipLaunchKernelGGL(out_kernel,   dim3(128), dim3(256), 0, stream,
                     fused, part2, gf, bfv, (float*)d_out);
}